// Round 3
// baseline (145.358 us; speedup 1.0000x reference)
//
#include <hip/hip_runtime.h>

#define T_DIM 4096
#define QPR 32   // float4 quads per (b,t) row (D=128)

__device__ __forceinline__ float4 ld4(const float4* __restrict__ p, int idx, bool ok) {
    float4 z = make_float4(0.f, 0.f, 0.f, 0.f);
    return ok ? p[idx] : z;
}

// One thread per float4 (4 consecutive d of one (b,t)).
// Branchless common path: priority-select over rows t+-1, t+-2 for all 4
// components (no need-bookkeeping, no fast-path branch). Guarded level-2
// (rows +-3..6) and cold serial level-3 for the rare deep gaps.
__global__ void __launch_bounds__(256) imputer_kernel(
    const float* __restrict__ x, float* __restrict__ out, int total4) {
    int i4 = blockIdx.x * blockDim.x + threadIdx.x;
    if (i4 >= total4) return;

    const float4* __restrict__ x4 = reinterpret_cast<const float4*>(x);
    float4 v = x4[i4];

    int q    = i4 & (QPR - 1);
    int row  = i4 >> 5;              // b*T + t
    int t    = row & (T_DIM - 1);
    int col0 = (row - t) * QPR + q;  // quad index at t=0, same (b,q)

    float vv[4] = {v.x, v.y, v.z, v.w};
    float av[4] = {0.f, 0.f, 0.f, 0.f};   // prev-valid value (0 = none found)
    float bv[4] = {0.f, 0.f, 0.f, 0.f};   // next-valid value
    int   si[4] = {-1, -1, -1, -1};
    int   ei[4] = {T_DIM, T_DIM, T_DIM, T_DIM};

    // ---- level-1 backward: rows t-1, t-2 (branchless priority select) ----
    {
        float4 r1 = ld4(x4, col0 + (t - 1) * QPR, t >= 1);
        float4 r2 = ld4(x4, col0 + (t - 2) * QPR, t >= 2);
        float p1[4] = {r1.x, r1.y, r1.z, r1.w};
        float p2[4] = {r2.x, r2.y, r2.z, r2.w};
#pragma unroll
        for (int c = 0; c < 4; ++c) {
            if (p2[c] != 0.f) { av[c] = p2[c]; si[c] = t - 2; }
            if (p1[c] != 0.f) { av[c] = p1[c]; si[c] = t - 1; }
        }
    }
    // ---- level-1 forward: rows t+1, t+2 ----
    {
        float4 r1 = ld4(x4, col0 + (t + 1) * QPR, t + 1 < T_DIM);
        float4 r2 = ld4(x4, col0 + (t + 2) * QPR, t + 2 < T_DIM);
        float p1[4] = {r1.x, r1.y, r1.z, r1.w};
        float p2[4] = {r2.x, r2.y, r2.z, r2.w};
#pragma unroll
        for (int c = 0; c < 4; ++c) {
            if (p2[c] != 0.f) { bv[c] = p2[c]; ei[c] = t + 2; }
            if (p1[c] != 0.f) { bv[c] = p1[c]; ei[c] = t + 1; }
        }
    }

    // ---- level-2: rows t-3..t-6 / t+3..t+6, only for unresolved lanes ----
    bool needB = false, needF = false;
#pragma unroll
    for (int c = 0; c < 4; ++c) {
        needB = needB || (vv[c] == 0.f && av[c] == 0.f);
        needF = needF || (vv[c] == 0.f && bv[c] == 0.f);
    }
    needB = needB && (t > 2);
    needF = needF && (t + 3 < T_DIM);

    if (__any(needB)) {
        if (needB) {
            float4 r3 = ld4(x4, col0 + (t - 3) * QPR, t >= 3);
            float4 r4 = ld4(x4, col0 + (t - 4) * QPR, t >= 4);
            float4 r5 = ld4(x4, col0 + (t - 5) * QPR, t >= 5);
            float4 r6 = ld4(x4, col0 + (t - 6) * QPR, t >= 6);
            float p3[4] = {r3.x, r3.y, r3.z, r3.w};
            float p4[4] = {r4.x, r4.y, r4.z, r4.w};
            float p5[4] = {r5.x, r5.y, r5.z, r5.w};
            float p6[4] = {r6.x, r6.y, r6.z, r6.w};
#pragma unroll
            for (int c = 0; c < 4; ++c) {
                float a2 = 0.f; int s2 = -1;
                if (p6[c] != 0.f) { a2 = p6[c]; s2 = t - 6; }
                if (p5[c] != 0.f) { a2 = p5[c]; s2 = t - 5; }
                if (p4[c] != 0.f) { a2 = p4[c]; s2 = t - 4; }
                if (p3[c] != 0.f) { a2 = p3[c]; s2 = t - 3; }
                if (av[c] == 0.f && a2 != 0.f) { av[c] = a2; si[c] = s2; }
            }
        }
    }
    if (__any(needF)) {
        if (needF) {
            float4 r3 = ld4(x4, col0 + (t + 3) * QPR, t + 3 < T_DIM);
            float4 r4 = ld4(x4, col0 + (t + 4) * QPR, t + 4 < T_DIM);
            float4 r5 = ld4(x4, col0 + (t + 5) * QPR, t + 5 < T_DIM);
            float4 r6 = ld4(x4, col0 + (t + 6) * QPR, t + 6 < T_DIM);
            float p3[4] = {r3.x, r3.y, r3.z, r3.w};
            float p4[4] = {r4.x, r4.y, r4.z, r4.w};
            float p5[4] = {r5.x, r5.y, r5.z, r5.w};
            float p6[4] = {r6.x, r6.y, r6.z, r6.w};
#pragma unroll
            for (int c = 0; c < 4; ++c) {
                float b2 = 0.f; int e2 = T_DIM;
                if (p6[c] != 0.f) { b2 = p6[c]; e2 = t + 6; }
                if (p5[c] != 0.f) { b2 = p5[c]; e2 = t + 5; }
                if (p4[c] != 0.f) { b2 = p4[c]; e2 = t + 4; }
                if (p3[c] != 0.f) { b2 = p3[c]; e2 = t + 3; }
                if (bv[c] == 0.f && b2 != 0.f) { bv[c] = b2; ei[c] = e2; }
            }
        }
    }

    // ---- level-3: cold serial walk beyond distance 6 ----
    bool stillB = false, stillF = false;
#pragma unroll
    for (int c = 0; c < 4; ++c) {
        stillB = stillB || (vv[c] == 0.f && av[c] == 0.f);
        stillF = stillF || (vv[c] == 0.f && bv[c] == 0.f);
    }
    stillB = stillB && (t > 6);
    stillF = stillF && (t + 7 < T_DIM);

    if (__any(stillB)) {
        if (stillB) {
#pragma unroll
            for (int c = 0; c < 4; ++c) {
                if (vv[c] == 0.f && av[c] == 0.f) {
                    int s = t - 7;
                    while (s >= 0 && x[(col0 + s * QPR) * 4 + c] == 0.f) --s;
                    if (s >= 0) { si[c] = s; av[c] = x[(col0 + s * QPR) * 4 + c]; }
                }
            }
        }
    }
    if (__any(stillF)) {
        if (stillF) {
#pragma unroll
            for (int c = 0; c < 4; ++c) {
                if (vv[c] == 0.f && bv[c] == 0.f) {
                    int e = t + 7;
                    while (e < T_DIM && x[(col0 + e * QPR) * 4 + c] == 0.f) ++e;
                    if (e < T_DIM) { ei[c] = e; bv[c] = x[(col0 + e * QPR) * 4 + c]; }
                }
            }
        }
    }

    // ---- epilogue: reference fill semantics, approximate rcp ----
    float res[4];
#pragma unroll
    for (int c = 0; c < 4; ++c) {
        int start = si[c] < 0 ? 0 : si[c];
        int end   = ei[c] < T_DIM ? ei[c] : T_DIM - 1;
        float a = av[c], b = bv[c];
        int denom = end - start - 1;
        float fill = a + (float)(t - start) * (b - a) * __builtin_amdgcn_rcpf((float)denom);
        if (denom <= 0) fill = a;
        if (start >= end || t >= end) fill = 0.f;
        res[c] = (vv[c] != 0.f) ? vv[c] : fill;
    }

    float4 o;
    o.x = res[0]; o.y = res[1]; o.z = res[2]; o.w = res[3];
    reinterpret_cast<float4*>(out)[i4] = o;
}

extern "C" void kernel_launch(void* const* d_in, const int* in_sizes, int n_in,
                              void* d_out, int out_size, void* d_ws, size_t ws_size,
                              hipStream_t stream) {
    const float* x = (const float*)d_in[0];
    float* out = (float*)d_out;
    int total4 = in_sizes[0] / 4;
    int threads = 256;
    int blocks = (total4 + threads - 1) / threads;
    imputer_kernel<<<blocks, threads, 0, stream>>>(x, out, total4);
}

// Round 4
// 71.612 us; speedup vs baseline: 2.0298x; 2.0298x over previous
//
#include <hip/hip_runtime.h>

#define T_DIM 4096
#define QPR 32   // float4 quads per (b,t) row (D=128)

// One thread per float4 (4 consecutive d of one (b,t)).
// All common-path loads are UNCONDITIONAL with clamped row indices
// (always in-bounds) -> no exec-mask churn, full load ILP.
// Merge rules make clamping semantically free:
//  - level-1: far-to-near, nearer check overrides clamped duplicates.
//  - level-2: nearest-first with found-guard; a boundary row's true-index
//    check always precedes its clamped duplicates.
__global__ void __launch_bounds__(256) imputer_kernel(
    const float* __restrict__ x, float* __restrict__ out, int total4) {
    int i4 = blockIdx.x * blockDim.x + threadIdx.x;
    if (i4 >= total4) return;

    const float4* __restrict__ x4 = reinterpret_cast<const float4*>(x);

    int q    = i4 & (QPR - 1);
    int row  = i4 >> 5;              // b*T + t
    int t    = row & (T_DIM - 1);
    int base = (row - t) * QPR + q;  // quad index at t=0, same (b,q)

    // ---- unconditional clamped loads: v, t-1, t-2, t+1, t+2 ----
    float4 v  = x4[i4];
    float4 m1 = x4[base + max(t - 1, 0) * QPR];
    float4 m2 = x4[base + max(t - 2, 0) * QPR];
    float4 p1 = x4[base + min(t + 1, T_DIM - 1) * QPR];
    float4 p2 = x4[base + min(t + 2, T_DIM - 1) * QPR];

    float vv[4] = {v.x, v.y, v.z, v.w};
    float M1[4] = {m1.x, m1.y, m1.z, m1.w};
    float M2[4] = {m2.x, m2.y, m2.z, m2.w};
    float P1[4] = {p1.x, p1.y, p1.z, p1.w};
    float P2[4] = {p2.x, p2.y, p2.z, p2.w};

    float A[4] = {0.f, 0.f, 0.f, 0.f};   // prev-valid value (0 = not found)
    float Bv[4] = {0.f, 0.f, 0.f, 0.f};  // next-valid value
    int   S[4] = {-1, -1, -1, -1};
    int   E[4] = {T_DIM, T_DIM, T_DIM, T_DIM};

#pragma unroll
    for (int c = 0; c < 4; ++c) {
        // backward level-1: far-to-near (near overrides)
        if (M2[c] != 0.f) { A[c] = M2[c]; S[c] = t - 2; }
        if (M1[c] != 0.f) { A[c] = M1[c]; S[c] = t - 1; }
        // forward level-1
        if (P2[c] != 0.f) { Bv[c] = P2[c]; E[c] = t + 2; }
        if (P1[c] != 0.f) { Bv[c] = P1[c]; E[c] = t + 1; }
    }

    // ---- level-2: rows +-3..6, wave-uniform entry, unconditional loads ----
    bool needB = false, needF = false;
#pragma unroll
    for (int c = 0; c < 4; ++c) {
        needB = needB || (vv[c] == 0.f && A[c] == 0.f);
        needF = needF || (vv[c] == 0.f && Bv[c] == 0.f);
    }

    if (__any(needB && t > 2)) {
        float4 r3 = x4[base + max(t - 3, 0) * QPR];
        float4 r4 = x4[base + max(t - 4, 0) * QPR];
        float4 r5 = x4[base + max(t - 5, 0) * QPR];
        float4 r6 = x4[base + max(t - 6, 0) * QPR];
        float R3[4] = {r3.x, r3.y, r3.z, r3.w};
        float R4[4] = {r4.x, r4.y, r4.z, r4.w};
        float R5[4] = {r5.x, r5.y, r5.z, r5.w};
        float R6[4] = {r6.x, r6.y, r6.z, r6.w};
#pragma unroll
        for (int c = 0; c < 4; ++c) {
            // nearest-first, found-guarded
            if (A[c] == 0.f && R3[c] != 0.f) { A[c] = R3[c]; S[c] = t - 3; }
            if (A[c] == 0.f && R4[c] != 0.f) { A[c] = R4[c]; S[c] = t - 4; }
            if (A[c] == 0.f && R5[c] != 0.f) { A[c] = R5[c]; S[c] = t - 5; }
            if (A[c] == 0.f && R6[c] != 0.f) { A[c] = R6[c]; S[c] = t - 6; }
        }
    }
    if (__any(needF && t + 3 < T_DIM)) {
        float4 r3 = x4[base + min(t + 3, T_DIM - 1) * QPR];
        float4 r4 = x4[base + min(t + 4, T_DIM - 1) * QPR];
        float4 r5 = x4[base + min(t + 5, T_DIM - 1) * QPR];
        float4 r6 = x4[base + min(t + 6, T_DIM - 1) * QPR];
        float R3[4] = {r3.x, r3.y, r3.z, r3.w};
        float R4[4] = {r4.x, r4.y, r4.z, r4.w};
        float R5[4] = {r5.x, r5.y, r5.z, r5.w};
        float R6[4] = {r6.x, r6.y, r6.z, r6.w};
#pragma unroll
        for (int c = 0; c < 4; ++c) {
            if (Bv[c] == 0.f && R3[c] != 0.f) { Bv[c] = R3[c]; E[c] = t + 3; }
            if (Bv[c] == 0.f && R4[c] != 0.f) { Bv[c] = R4[c]; E[c] = t + 4; }
            if (Bv[c] == 0.f && R5[c] != 0.f) { Bv[c] = R5[c]; E[c] = t + 5; }
            if (Bv[c] == 0.f && R6[c] != 0.f) { Bv[c] = R6[c]; E[c] = t + 6; }
        }
    }

    // ---- level-3: cold serial walk beyond distance 6 ----
    bool stillB = false, stillF = false;
#pragma unroll
    for (int c = 0; c < 4; ++c) {
        stillB = stillB || (vv[c] == 0.f && A[c] == 0.f);
        stillF = stillF || (vv[c] == 0.f && Bv[c] == 0.f);
    }
    if (__any(stillB && t > 6)) {
        if (stillB) {
#pragma unroll
            for (int c = 0; c < 4; ++c) {
                if (vv[c] == 0.f && A[c] == 0.f) {
                    int s = t - 7;
                    while (s >= 0 && x[(base + s * QPR) * 4 + c] == 0.f) --s;
                    if (s >= 0) { S[c] = s; A[c] = x[(base + s * QPR) * 4 + c]; }
                }
            }
        }
    }
    if (__any(stillF && t + 7 < T_DIM)) {
        if (stillF) {
#pragma unroll
            for (int c = 0; c < 4; ++c) {
                if (vv[c] == 0.f && Bv[c] == 0.f) {
                    int e = t + 7;
                    while (e < T_DIM && x[(base + e * QPR) * 4 + c] == 0.f) ++e;
                    if (e < T_DIM) { E[c] = e; Bv[c] = x[(base + e * QPR) * 4 + c]; }
                }
            }
        }
    }

    // ---- epilogue: reference fill semantics, approximate rcp ----
    float res[4];
#pragma unroll
    for (int c = 0; c < 4; ++c) {
        int start = S[c] < 0 ? 0 : S[c];
        int end   = E[c] < T_DIM ? E[c] : T_DIM - 1;
        float a = A[c], b = Bv[c];
        int denom = end - start - 1;
        float fill = a + (float)(t - start) * (b - a) * __builtin_amdgcn_rcpf((float)denom);
        if (denom <= 0) fill = a;
        if (start >= end || t >= end) fill = 0.f;
        res[c] = (vv[c] != 0.f) ? vv[c] : fill;
    }

    float4 o;
    o.x = res[0]; o.y = res[1]; o.z = res[2]; o.w = res[3];
    reinterpret_cast<float4*>(out)[i4] = o;
}

extern "C" void kernel_launch(void* const* d_in, const int* in_sizes, int n_in,
                              void* d_out, int out_size, void* d_ws, size_t ws_size,
                              hipStream_t stream) {
    const float* x = (const float*)d_in[0];
    float* out = (float*)d_out;
    int total4 = in_sizes[0] / 4;
    int threads = 256;
    int blocks = (total4 + threads - 1) / threads;
    imputer_kernel<<<blocks, threads, 0, stream>>>(x, out, total4);
}

// Round 5
// 63.693 us; speedup vs baseline: 2.2821x; 1.1243x over previous
//
#include <hip/hip_runtime.h>

#define T_DIM 4096
#define QPR 32   // float4 quads per (b,t) row (D=128)

// One thread per float4 (4 consecutive d of one (b,t)).
// Level-1: 3 unconditional clamped row loads per direction (7 loads total
// upfront, all independent -> one latency round-trip, ~40+ VGPRs in flight).
// Level-2 (rows +-4..8): entered by ~12% of waves. Level-3 serial walk:
// ~1e-5 of waves.
// Clamping is semantically free:
//  - level-1 merges far-to-near: the true-index check of a boundary row
//    always comes after (and overrides) its clamped duplicates.
//  - level-2 merges nearest-first with found-guard: the true-index check
//    always comes before its clamped duplicates.
__global__ void __launch_bounds__(256) imputer_kernel(
    const float* __restrict__ x, float* __restrict__ out, int total4) {
    int i4 = blockIdx.x * blockDim.x + threadIdx.x;
    if (i4 >= total4) return;

    const float4* __restrict__ x4 = reinterpret_cast<const float4*>(x);

    int q    = i4 & (QPR - 1);
    int row  = i4 >> 5;              // b*T + t
    int t    = row & (T_DIM - 1);
    int base = (row - t) * QPR + q;  // quad index at t=0, same (b,q)

    // ---- 7 unconditional clamped loads, all issued upfront ----
    float4 v  = x4[i4];
    float4 m1 = x4[base + max(t - 1, 0) * QPR];
    float4 m2 = x4[base + max(t - 2, 0) * QPR];
    float4 m3 = x4[base + max(t - 3, 0) * QPR];
    float4 p1 = x4[base + min(t + 1, T_DIM - 1) * QPR];
    float4 p2 = x4[base + min(t + 2, T_DIM - 1) * QPR];
    float4 p3 = x4[base + min(t + 3, T_DIM - 1) * QPR];

    float vv[4] = {v.x, v.y, v.z, v.w};
    float M1[4] = {m1.x, m1.y, m1.z, m1.w};
    float M2[4] = {m2.x, m2.y, m2.z, m2.w};
    float M3[4] = {m3.x, m3.y, m3.z, m3.w};
    float P1[4] = {p1.x, p1.y, p1.z, p1.w};
    float P2[4] = {p2.x, p2.y, p2.z, p2.w};
    float P3[4] = {p3.x, p3.y, p3.z, p3.w};

    float A[4]  = {0.f, 0.f, 0.f, 0.f};   // prev-valid value (0 = not found)
    float Bv[4] = {0.f, 0.f, 0.f, 0.f};   // next-valid value
    int   S[4]  = {-1, -1, -1, -1};
    int   E[4]  = {T_DIM, T_DIM, T_DIM, T_DIM};

#pragma unroll
    for (int c = 0; c < 4; ++c) {
        // far-to-near (near overrides clamped duplicates)
        if (M3[c] != 0.f) { A[c] = M3[c]; S[c] = t - 3; }
        if (M2[c] != 0.f) { A[c] = M2[c]; S[c] = t - 2; }
        if (M1[c] != 0.f) { A[c] = M1[c]; S[c] = t - 1; }
        if (P3[c] != 0.f) { Bv[c] = P3[c]; E[c] = t + 3; }
        if (P2[c] != 0.f) { Bv[c] = P2[c]; E[c] = t + 2; }
        if (P1[c] != 0.f) { Bv[c] = P1[c]; E[c] = t + 1; }
    }

    // ---- cheap need detection: min over comps of |vv|+|found| == 0 ----
    float nb = fminf(fminf(fabsf(vv[0]) + fabsf(A[0]),  fabsf(vv[1]) + fabsf(A[1])),
                     fminf(fabsf(vv[2]) + fabsf(A[2]),  fabsf(vv[3]) + fabsf(A[3])));
    float nf = fminf(fminf(fabsf(vv[0]) + fabsf(Bv[0]), fabsf(vv[1]) + fabsf(Bv[1])),
                     fminf(fabsf(vv[2]) + fabsf(Bv[2]), fabsf(vv[3]) + fabsf(Bv[3])));

    // ---- level-2: rows +-4..8, wave-uniform entry, unconditional loads ----
    if (__any(nb == 0.f && t > 3)) {
        float4 r4 = x4[base + max(t - 4, 0) * QPR];
        float4 r5 = x4[base + max(t - 5, 0) * QPR];
        float4 r6 = x4[base + max(t - 6, 0) * QPR];
        float4 r7 = x4[base + max(t - 7, 0) * QPR];
        float4 r8 = x4[base + max(t - 8, 0) * QPR];
        float R4[4] = {r4.x, r4.y, r4.z, r4.w};
        float R5[4] = {r5.x, r5.y, r5.z, r5.w};
        float R6[4] = {r6.x, r6.y, r6.z, r6.w};
        float R7[4] = {r7.x, r7.y, r7.z, r7.w};
        float R8[4] = {r8.x, r8.y, r8.z, r8.w};
#pragma unroll
        for (int c = 0; c < 4; ++c) {
            // nearest-first, found-guarded
            if (A[c] == 0.f && R4[c] != 0.f) { A[c] = R4[c]; S[c] = t - 4; }
            if (A[c] == 0.f && R5[c] != 0.f) { A[c] = R5[c]; S[c] = t - 5; }
            if (A[c] == 0.f && R6[c] != 0.f) { A[c] = R6[c]; S[c] = t - 6; }
            if (A[c] == 0.f && R7[c] != 0.f) { A[c] = R7[c]; S[c] = t - 7; }
            if (A[c] == 0.f && R8[c] != 0.f) { A[c] = R8[c]; S[c] = t - 8; }
        }
    }
    if (__any(nf == 0.f && t + 4 < T_DIM)) {
        float4 r4 = x4[base + min(t + 4, T_DIM - 1) * QPR];
        float4 r5 = x4[base + min(t + 5, T_DIM - 1) * QPR];
        float4 r6 = x4[base + min(t + 6, T_DIM - 1) * QPR];
        float4 r7 = x4[base + min(t + 7, T_DIM - 1) * QPR];
        float4 r8 = x4[base + min(t + 8, T_DIM - 1) * QPR];
        float R4[4] = {r4.x, r4.y, r4.z, r4.w};
        float R5[4] = {r5.x, r5.y, r5.z, r5.w};
        float R6[4] = {r6.x, r6.y, r6.z, r6.w};
        float R7[4] = {r7.x, r7.y, r7.z, r7.w};
        float R8[4] = {r8.x, r8.y, r8.z, r8.w};
#pragma unroll
        for (int c = 0; c < 4; ++c) {
            if (Bv[c] == 0.f && R4[c] != 0.f) { Bv[c] = R4[c]; E[c] = t + 4; }
            if (Bv[c] == 0.f && R5[c] != 0.f) { Bv[c] = R5[c]; E[c] = t + 5; }
            if (Bv[c] == 0.f && R6[c] != 0.f) { Bv[c] = R6[c]; E[c] = t + 6; }
            if (Bv[c] == 0.f && R7[c] != 0.f) { Bv[c] = R7[c]; E[c] = t + 7; }
            if (Bv[c] == 0.f && R8[c] != 0.f) { Bv[c] = R8[c]; E[c] = t + 8; }
        }
    }

    // ---- level-3: cold serial walk beyond distance 8 (~1e-5 of waves) ----
    bool stillB = false, stillF = false;
#pragma unroll
    for (int c = 0; c < 4; ++c) {
        stillB = stillB || (vv[c] == 0.f && A[c] == 0.f);
        stillF = stillF || (vv[c] == 0.f && Bv[c] == 0.f);
    }
    if (__any(stillB && t > 8)) {
        if (stillB) {
#pragma unroll
            for (int c = 0; c < 4; ++c) {
                if (vv[c] == 0.f && A[c] == 0.f) {
                    int s = t - 9;
                    while (s >= 0 && x[(base + s * QPR) * 4 + c] == 0.f) --s;
                    if (s >= 0) { S[c] = s; A[c] = x[(base + s * QPR) * 4 + c]; }
                }
            }
        }
    }
    if (__any(stillF && t + 9 < T_DIM)) {
        if (stillF) {
#pragma unroll
            for (int c = 0; c < 4; ++c) {
                if (vv[c] == 0.f && Bv[c] == 0.f) {
                    int e = t + 9;
                    while (e < T_DIM && x[(base + e * QPR) * 4 + c] == 0.f) ++e;
                    if (e < T_DIM) { E[c] = e; Bv[c] = x[(base + e * QPR) * 4 + c]; }
                }
            }
        }
    }

    // ---- epilogue: reference fill semantics, trimmed ----
    // start <= t always  =>  (start>=end) implies (t>=end): one keep-cond.
    // denom==0  =>  t==start  =>  t_rel==0  =>  fill==A: max(denom,1) suffices.
    float res[4];
#pragma unroll
    for (int c = 0; c < 4; ++c) {
        int start = max(S[c], 0);
        int end   = min(E[c], T_DIM - 1);
        float denom_f = fmaxf((float)(end - start - 1), 1.0f);
        float fill = A[c] + (float)(t - start) * (Bv[c] - A[c]) * __builtin_amdgcn_rcpf(denom_f);
        res[c] = (vv[c] != 0.f || t >= end) ? vv[c] : fill;
    }

    float4 o;
    o.x = res[0]; o.y = res[1]; o.z = res[2]; o.w = res[3];
    reinterpret_cast<float4*>(out)[i4] = o;
}

extern "C" void kernel_launch(void* const* d_in, const int* in_sizes, int n_in,
                              void* d_out, int out_size, void* d_ws, size_t ws_size,
                              hipStream_t stream) {
    const float* x = (const float*)d_in[0];
    float* out = (float*)d_out;
    int total4 = in_sizes[0] / 4;
    int threads = 256;
    int blocks = (total4 + threads - 1) / threads;
    imputer_kernel<<<blocks, threads, 0, stream>>>(x, out, total4);
}

// Round 6
// 47.409 us; speedup vs baseline: 3.0660x; 1.3435x over previous
//
#include <hip/hip_runtime.h>

#define T_DIM 4096
#define QPR 32            // float4 quads per (b,t) row (D=128)
#define CH 8              // chunk length along t
#define CPS (T_DIM / CH)  // 512 chunks per series

// One thread owns CH=8 consecutive t's of one (b, 4-d) column.
// Forward register scan -> (a, kb); backward register scan -> (b, kf);
// epilogue is branch/select-free:
//   fill = a + t_rel*(b-a)*rcp(max3(t_rel+kf-1, t_rel, 1))
//   valid: kb=0 -> t_rel=0 -> fill==a exactly.
//   t>=end (kf=0, only at series tail): b=0 -> fill ~ a*2^-23 ~ 0.
// Halo init per direction: 4 clamped unconditional rows, nearest-first
// found-guarded merge with distance clamps min(j,kbmax)/min(j+1,kfmax)
// (reproduces s=-1 / end=T-1 sentinel semantics); deeper gaps (P~0.15^5
// per comp) take a guarded cold serial walk.
__global__ void __launch_bounds__(256) imputer_kernel(
    const float* __restrict__ x, float* __restrict__ out) {
    int n  = blockIdx.x * blockDim.x + threadIdx.x;
    int q  = n & (QPR - 1);
    int ch = n >> 5;                  // global chunk id
    int t0 = (ch & (CPS - 1)) << 3;
    int bb = ch >> 9;
    int sb = bb * (T_DIM * QPR) + q;  // quad index of (bb, t=0, q)
    int base = sb + t0 * QPR;

    const float4* __restrict__ x4 = reinterpret_cast<const float4*>(x);

    // ---- chunk rows: one base, immediate offsets 0..7*512B ----
    float4 R[CH];
#pragma unroll
    for (int k = 0; k < CH; ++k) R[k] = x4[base + k * QPR];

    // ---- halo rows, clamped & unconditional ----
    float4 PM[4], PS[4];
#pragma unroll
    for (int j = 0; j < 4; ++j) {
        PM[j] = x4[sb + max(t0 - 1 - j, 0) * QPR];
        PS[j] = x4[sb + min(t0 + CH + j, T_DIM - 1) * QPR];
    }

    float Rv[CH][4];
#pragma unroll
    for (int k = 0; k < CH; ++k) {
        Rv[k][0] = R[k].x; Rv[k][1] = R[k].y; Rv[k][2] = R[k].z; Rv[k][3] = R[k].w;
    }
    float PMv[4][4], PSv[4][4];
#pragma unroll
    for (int j = 0; j < 4; ++j) {
        PMv[j][0] = PM[j].x; PMv[j][1] = PM[j].y; PMv[j][2] = PM[j].z; PMv[j][3] = PM[j].w;
        PSv[j][0] = PS[j].x; PSv[j][1] = PS[j].y; PSv[j][2] = PS[j].z; PSv[j][3] = PS[j].w;
    }

    // ---- prefix merge: state (A, KB) at position t0-1 ----
    float kbmax = (float)max(t0 - 1, 0);
    float A[4], KB[4];
#pragma unroll
    for (int c = 0; c < 4; ++c) { A[c] = 0.f; KB[c] = (float)t0; }  // s=-1 default
#pragma unroll
    for (int j = 0; j < 4; ++j) {
        float kbj = fminf((float)j, kbmax);
#pragma unroll
        for (int c = 0; c < 4; ++c)
            if (A[c] == 0.f && PMv[j][c] != 0.f) { A[c] = PMv[j][c]; KB[c] = kbj; }
    }

    // ---- suffix merge: state (Bt, KF) at position t_end = t0+CH-1 ----
    float kfmax = (float)(T_DIM - CH - t0);   // = (T-1) - t_end
    float Bt[4], KF[4];
#pragma unroll
    for (int c = 0; c < 4; ++c) { Bt[c] = 0.f; KF[c] = kfmax; }  // nv=T default
#pragma unroll
    for (int j = 0; j < 4; ++j) {
        float kfj = fminf((float)(j + 1), kfmax);
#pragma unroll
        for (int c = 0; c < 4; ++c)
            if (Bt[c] == 0.f && PSv[j][c] != 0.f) { Bt[c] = PSv[j][c]; KF[c] = kfj; }
    }

    // ---- deep halo (rare): gap extends past the 4 shallow rows ----
    bool nb = false, nf = false;
#pragma unroll
    for (int c = 0; c < 4; ++c) {
        nb = nb || (A[c] == 0.f && Rv[0][c] == 0.f);
        nf = nf || (Bt[c] == 0.f && Rv[CH - 1][c] == 0.f);
    }
    if (__any(nb && t0 > 4)) {
        if (nb && t0 > 4) {
#pragma unroll
            for (int c = 0; c < 4; ++c) {
                if (A[c] == 0.f && Rv[0][c] == 0.f) {
                    int s = t0 - 5;
                    while (s >= 0 && x[(sb + s * QPR) * 4 + c] == 0.f) --s;
                    if (s >= 0) { A[c] = x[(sb + s * QPR) * 4 + c]; KB[c] = (float)(t0 - 1 - s); }
                    // else: default (A=0, KB=t0) is the correct s=-1 state
                }
            }
        }
    }
    if (__any(nf && (t0 + 12) < T_DIM)) {
        if (nf && (t0 + 12) < T_DIM) {
#pragma unroll
            for (int c = 0; c < 4; ++c) {
                if (Bt[c] == 0.f && Rv[CH - 1][c] == 0.f) {
                    int e = t0 + CH + 4;
                    while (e < T_DIM && x[(sb + e * QPR) * 4 + c] == 0.f) ++e;
                    if (e < T_DIM) { Bt[c] = x[(sb + e * QPR) * 4 + c]; KF[c] = (float)(e - (t0 + CH - 1)); }
                    else           { KF[c] = kfmax; }  // whole tail invalid: b=0, end=T-1
                }
            }
        }
    }

    // ---- forward sweep: per-position (a, kb) ----
    float av[CH][4], kb[CH][4];
#pragma unroll
    for (int k = 0; k < CH; ++k) {
#pragma unroll
        for (int c = 0; c < 4; ++c) {
            bool valid = (Rv[k][c] != 0.f);
            A[c]  = valid ? Rv[k][c] : A[c];
            KB[c] = valid ? 0.f : (KB[c] + 1.f);
            av[k][c] = A[c];
            kb[k][c] = KB[c];
        }
    }

    // ---- backward sweep + select-free epilogue + store ----
    float tf = (float)t0;
#pragma unroll
    for (int k = CH - 1; k >= 0; --k) {
        float o[4];
#pragma unroll
        for (int c = 0; c < 4; ++c) {
            float trel = fminf(kb[k][c], tf + (float)k);          // min(kb, t)
            float u    = trel + KF[c] - 1.f;                      // denom
            float den  = fmaxf(fmaxf(u, trel), 1.f);              // v_max3
            o[c] = av[k][c] + trel * (Bt[c] - av[k][c]) * __builtin_amdgcn_rcpf(den);
            bool valid = (kb[k][c] == 0.f);
            Bt[c] = valid ? av[k][c] : Bt[c];
            KF[c] = valid ? 1.f : (KF[c] + 1.f);
        }
        float4 ov = make_float4(o[0], o[1], o[2], o[3]);
        reinterpret_cast<float4*>(out)[base + k * QPR] = ov;
    }
}

extern "C" void kernel_launch(void* const* d_in, const int* in_sizes, int n_in,
                              void* d_out, int out_size, void* d_ws, size_t ws_size,
                              hipStream_t stream) {
    const float* x = (const float*)d_in[0];
    float* out = (float*)d_out;
    // threads = B * (T/CH) * QPR = 64*512*32 = 1,048,576 exactly
    int total = (in_sizes[0] / 4) / CH * 1;  // = 1048576
    int threads = 256;
    int blocks = total / threads;            // 4096, exact
    imputer_kernel<<<blocks, threads, 0, stream>>>(x, out);
}

// Round 8
// 46.057 us; speedup vs baseline: 3.1560x; 1.0294x over previous
//
#include <hip/hip_runtime.h>

#define T_DIM 4096
#define QPR 32            // float4 quads per (b,t) row (D=128)
#define CH 8              // chunk length along t
#define CPS (T_DIM / CH)  // 512 chunks per series

typedef float floatx4 __attribute__((ext_vector_type(4)));  // native vec for NT store

// One thread owns CH=8 consecutive t's of one (b, 4-d) column.
// Forward register scan -> (a, kb); backward register scan -> (b, kf);
// epilogue is branch/select-free:
//   fill = a + t_rel*(b-a)*rcp(max3(t_rel+kf-1, t_rel, 1))
//   valid: kb=0 -> t_rel=0 -> fill==a exactly.
//   t>=end (kf=0, only at series tail): b=0 -> fill ~ a*2^-23 ~ 0.
// Output is write-once -> NON-TEMPORAL stores: skip L2 allocate so the
// write stream doesn't evict the L3-resident input lines.
__global__ void __launch_bounds__(256) imputer_kernel(
    const float* __restrict__ x, float* __restrict__ out) {
    int n  = blockIdx.x * blockDim.x + threadIdx.x;
    int q  = n & (QPR - 1);
    int ch = n >> 5;                  // global chunk id
    int t0 = (ch & (CPS - 1)) << 3;
    int bb = ch >> 9;
    int sb = bb * (T_DIM * QPR) + q;  // quad index of (bb, t=0, q)
    int base = sb + t0 * QPR;

    const float4* __restrict__ x4 = reinterpret_cast<const float4*>(x);

    // ---- chunk rows: one base, immediate offsets ----
    float4 R[CH];
#pragma unroll
    for (int k = 0; k < CH; ++k) R[k] = x4[base + k * QPR];

    // ---- halo rows, clamped & unconditional ----
    float4 PM[4], PS[4];
#pragma unroll
    for (int j = 0; j < 4; ++j) {
        PM[j] = x4[sb + max(t0 - 1 - j, 0) * QPR];
        PS[j] = x4[sb + min(t0 + CH + j, T_DIM - 1) * QPR];
    }

    float Rv[CH][4];
#pragma unroll
    for (int k = 0; k < CH; ++k) {
        Rv[k][0] = R[k].x; Rv[k][1] = R[k].y; Rv[k][2] = R[k].z; Rv[k][3] = R[k].w;
    }
    float PMv[4][4], PSv[4][4];
#pragma unroll
    for (int j = 0; j < 4; ++j) {
        PMv[j][0] = PM[j].x; PMv[j][1] = PM[j].y; PMv[j][2] = PM[j].z; PMv[j][3] = PM[j].w;
        PSv[j][0] = PS[j].x; PSv[j][1] = PS[j].y; PSv[j][2] = PS[j].z; PSv[j][3] = PS[j].w;
    }

    // ---- prefix merge: state (A, KB) at position t0-1 ----
    float kbmax = (float)max(t0 - 1, 0);
    float A[4], KB[4];
#pragma unroll
    for (int c = 0; c < 4; ++c) { A[c] = 0.f; KB[c] = (float)t0; }  // s=-1 default
#pragma unroll
    for (int j = 0; j < 4; ++j) {
        float kbj = fminf((float)j, kbmax);
#pragma unroll
        for (int c = 0; c < 4; ++c)
            if (A[c] == 0.f && PMv[j][c] != 0.f) { A[c] = PMv[j][c]; KB[c] = kbj; }
    }

    // ---- suffix merge: state (Bt, KF) at position t_end = t0+CH-1 ----
    float kfmax = (float)(T_DIM - CH - t0);   // = (T-1) - t_end
    float Bt[4], KF[4];
#pragma unroll
    for (int c = 0; c < 4; ++c) { Bt[c] = 0.f; KF[c] = kfmax; }  // nv=T default
#pragma unroll
    for (int j = 0; j < 4; ++j) {
        float kfj = fminf((float)(j + 1), kfmax);
#pragma unroll
        for (int c = 0; c < 4; ++c)
            if (Bt[c] == 0.f && PSv[j][c] != 0.f) { Bt[c] = PSv[j][c]; KF[c] = kfj; }
    }

    // ---- deep halo (rare): gap extends past the 4 shallow rows ----
    bool nb = false, nf = false;
#pragma unroll
    for (int c = 0; c < 4; ++c) {
        nb = nb || (A[c] == 0.f && Rv[0][c] == 0.f);
        nf = nf || (Bt[c] == 0.f && Rv[CH - 1][c] == 0.f);
    }
    if (__any(nb && t0 > 4)) {
        if (nb && t0 > 4) {
#pragma unroll
            for (int c = 0; c < 4; ++c) {
                if (A[c] == 0.f && Rv[0][c] == 0.f) {
                    int s = t0 - 5;
                    while (s >= 0 && x[(sb + s * QPR) * 4 + c] == 0.f) --s;
                    if (s >= 0) { A[c] = x[(sb + s * QPR) * 4 + c]; KB[c] = (float)(t0 - 1 - s); }
                    // else: default (A=0, KB=t0) is the correct s=-1 state
                }
            }
        }
    }
    if (__any(nf && (t0 + 12) < T_DIM)) {
        if (nf && (t0 + 12) < T_DIM) {
#pragma unroll
            for (int c = 0; c < 4; ++c) {
                if (Bt[c] == 0.f && Rv[CH - 1][c] == 0.f) {
                    int e = t0 + CH + 4;
                    while (e < T_DIM && x[(sb + e * QPR) * 4 + c] == 0.f) ++e;
                    if (e < T_DIM) { Bt[c] = x[(sb + e * QPR) * 4 + c]; KF[c] = (float)(e - (t0 + CH - 1)); }
                    else           { KF[c] = kfmax; }  // whole tail invalid: b=0, end=T-1
                }
            }
        }
    }

    // ---- forward sweep: per-position (a, kb) ----
    float av[CH][4], kb[CH][4];
#pragma unroll
    for (int k = 0; k < CH; ++k) {
#pragma unroll
        for (int c = 0; c < 4; ++c) {
            bool valid = (Rv[k][c] != 0.f);
            A[c]  = valid ? Rv[k][c] : A[c];
            KB[c] = valid ? 0.f : (KB[c] + 1.f);
            av[k][c] = A[c];
            kb[k][c] = KB[c];
        }
    }

    // ---- backward sweep + select-free epilogue + NT store ----
    float tf = (float)t0;
    floatx4* __restrict__ out4 = reinterpret_cast<floatx4*>(out);
#pragma unroll
    for (int k = CH - 1; k >= 0; --k) {
        float o[4];
#pragma unroll
        for (int c = 0; c < 4; ++c) {
            float trel = fminf(kb[k][c], tf + (float)k);          // min(kb, t)
            float u    = trel + KF[c] - 1.f;                      // denom
            float den  = fmaxf(fmaxf(u, trel), 1.f);              // v_max3
            o[c] = av[k][c] + trel * (Bt[c] - av[k][c]) * __builtin_amdgcn_rcpf(den);
            bool valid = (kb[k][c] == 0.f);
            Bt[c] = valid ? av[k][c] : Bt[c];
            KF[c] = valid ? 1.f : (KF[c] + 1.f);
        }
        floatx4 ov = {o[0], o[1], o[2], o[3]};
        __builtin_nontemporal_store(ov, &out4[base + k * QPR]);
    }
}

extern "C" void kernel_launch(void* const* d_in, const int* in_sizes, int n_in,
                              void* d_out, int out_size, void* d_ws, size_t ws_size,
                              hipStream_t stream) {
    const float* x = (const float*)d_in[0];
    float* out = (float*)d_out;
    int threads = 256;
    int blocks = (in_sizes[0] / 4 / CH) / threads;   // 4096, exact
    imputer_kernel<<<blocks, threads, 0, stream>>>(x, out);
}

// Round 9
// 45.998 us; speedup vs baseline: 3.1601x; 1.0013x over previous
//
#include <hip/hip_runtime.h>

#define T_DIM 4096
#define QPR 32            // float4 quads per (b,t) row (D=128)
#define CH 8              // chunk length along t
#define CPS (T_DIM / CH)  // 512 chunks per series

typedef float floatx4 __attribute__((ext_vector_type(4)));  // native vec for NT store

// One thread owns CH=8 consecutive t's of one (b, 4-d) column.
// Forward register scan -> (a, kb); backward register scan -> (b, kf);
// epilogue is branch/select-free:
//   fill = a + t_rel*(b-a)*rcp(max3(t_rel+kf-1, t_rel, 1))
// __launch_bounds__(256, 4): allow ~128 VGPRs so all 16 independent float4
// loads (8 chunk + 8 halo) are in flight in ONE latency round-trip.
// (At (256,8) the compiler allocated 44 VGPRs and serialized the loads
// into >=2 dependent batches; measured occupancy was only ~46% anyway.)
__global__ void __launch_bounds__(256, 4) imputer_kernel(
    const float* __restrict__ x, float* __restrict__ out) {
    int n  = blockIdx.x * blockDim.x + threadIdx.x;
    int q  = n & (QPR - 1);
    int ch = n >> 5;                  // global chunk id
    int t0 = (ch & (CPS - 1)) << 3;
    int bb = ch >> 9;
    int sb = bb * (T_DIM * QPR) + q;  // quad index of (bb, t=0, q)
    int base = sb + t0 * QPR;

    const float4* __restrict__ x4 = reinterpret_cast<const float4*>(x);

    // ---- all 16 loads issued upfront: 8 chunk rows + 4+4 clamped halo ----
    float4 R[CH];
#pragma unroll
    for (int k = 0; k < CH; ++k) R[k] = x4[base + k * QPR];

    float4 PM[4], PS[4];
#pragma unroll
    for (int j = 0; j < 4; ++j) {
        PM[j] = x4[sb + max(t0 - 1 - j, 0) * QPR];
        PS[j] = x4[sb + min(t0 + CH + j, T_DIM - 1) * QPR];
    }

    float Rv[CH][4];
#pragma unroll
    for (int k = 0; k < CH; ++k) {
        Rv[k][0] = R[k].x; Rv[k][1] = R[k].y; Rv[k][2] = R[k].z; Rv[k][3] = R[k].w;
    }
    float PMv[4][4], PSv[4][4];
#pragma unroll
    for (int j = 0; j < 4; ++j) {
        PMv[j][0] = PM[j].x; PMv[j][1] = PM[j].y; PMv[j][2] = PM[j].z; PMv[j][3] = PM[j].w;
        PSv[j][0] = PS[j].x; PSv[j][1] = PS[j].y; PSv[j][2] = PS[j].z; PSv[j][3] = PS[j].w;
    }

    // ---- prefix merge: state (A, KB) at position t0-1 ----
    float kbmax = (float)max(t0 - 1, 0);
    float A[4], KB[4];
#pragma unroll
    for (int c = 0; c < 4; ++c) { A[c] = 0.f; KB[c] = (float)t0; }  // s=-1 default
#pragma unroll
    for (int j = 0; j < 4; ++j) {
        float kbj = fminf((float)j, kbmax);
#pragma unroll
        for (int c = 0; c < 4; ++c)
            if (A[c] == 0.f && PMv[j][c] != 0.f) { A[c] = PMv[j][c]; KB[c] = kbj; }
    }

    // ---- suffix merge: state (Bt, KF) at position t_end = t0+CH-1 ----
    float kfmax = (float)(T_DIM - CH - t0);   // = (T-1) - t_end
    float Bt[4], KF[4];
#pragma unroll
    for (int c = 0; c < 4; ++c) { Bt[c] = 0.f; KF[c] = kfmax; }  // nv=T default
#pragma unroll
    for (int j = 0; j < 4; ++j) {
        float kfj = fminf((float)(j + 1), kfmax);
#pragma unroll
        for (int c = 0; c < 4; ++c)
            if (Bt[c] == 0.f && PSv[j][c] != 0.f) { Bt[c] = PSv[j][c]; KF[c] = kfj; }
    }

    // ---- deep halo (rare): gap extends past the 4 shallow rows ----
    bool nb = false, nf = false;
#pragma unroll
    for (int c = 0; c < 4; ++c) {
        nb = nb || (A[c] == 0.f && Rv[0][c] == 0.f);
        nf = nf || (Bt[c] == 0.f && Rv[CH - 1][c] == 0.f);
    }
    if (__any(nb && t0 > 4)) {
        if (nb && t0 > 4) {
#pragma unroll
            for (int c = 0; c < 4; ++c) {
                if (A[c] == 0.f && Rv[0][c] == 0.f) {
                    int s = t0 - 5;
                    while (s >= 0 && x[(sb + s * QPR) * 4 + c] == 0.f) --s;
                    if (s >= 0) { A[c] = x[(sb + s * QPR) * 4 + c]; KB[c] = (float)(t0 - 1 - s); }
                    // else: default (A=0, KB=t0) is the correct s=-1 state
                }
            }
        }
    }
    if (__any(nf && (t0 + 12) < T_DIM)) {
        if (nf && (t0 + 12) < T_DIM) {
#pragma unroll
            for (int c = 0; c < 4; ++c) {
                if (Bt[c] == 0.f && Rv[CH - 1][c] == 0.f) {
                    int e = t0 + CH + 4;
                    while (e < T_DIM && x[(sb + e * QPR) * 4 + c] == 0.f) ++e;
                    if (e < T_DIM) { Bt[c] = x[(sb + e * QPR) * 4 + c]; KF[c] = (float)(e - (t0 + CH - 1)); }
                    else           { KF[c] = kfmax; }  // whole tail invalid: b=0, end=T-1
                }
            }
        }
    }

    // ---- forward sweep: per-position (a, kb) ----
    float av[CH][4], kb[CH][4];
#pragma unroll
    for (int k = 0; k < CH; ++k) {
#pragma unroll
        for (int c = 0; c < 4; ++c) {
            bool valid = (Rv[k][c] != 0.f);
            A[c]  = valid ? Rv[k][c] : A[c];
            KB[c] = valid ? 0.f : (KB[c] + 1.f);
            av[k][c] = A[c];
            kb[k][c] = KB[c];
        }
    }

    // ---- backward sweep + select-free epilogue + NT store ----
    float tf = (float)t0;
    floatx4* __restrict__ out4 = reinterpret_cast<floatx4*>(out);
#pragma unroll
    for (int k = CH - 1; k >= 0; --k) {
        float o[4];
#pragma unroll
        for (int c = 0; c < 4; ++c) {
            float trel = fminf(kb[k][c], tf + (float)k);          // min(kb, t)
            float u    = trel + KF[c] - 1.f;                      // denom
            float den  = fmaxf(fmaxf(u, trel), 1.f);              // v_max3
            o[c] = av[k][c] + trel * (Bt[c] - av[k][c]) * __builtin_amdgcn_rcpf(den);
            bool valid = (kb[k][c] == 0.f);
            Bt[c] = valid ? av[k][c] : Bt[c];
            KF[c] = valid ? 1.f : (KF[c] + 1.f);
        }
        floatx4 ov = {o[0], o[1], o[2], o[3]};
        __builtin_nontemporal_store(ov, &out4[base + k * QPR]);
    }
}

extern "C" void kernel_launch(void* const* d_in, const int* in_sizes, int n_in,
                              void* d_out, int out_size, void* d_ws, size_t ws_size,
                              hipStream_t stream) {
    const float* x = (const float*)d_in[0];
    float* out = (float*)d_out;
    int threads = 256;
    int blocks = (in_sizes[0] / 4 / CH) / threads;   // 4096, exact
    imputer_kernel<<<blocks, threads, 0, stream>>>(x, out);
}

// Round 10
// 42.815 us; speedup vs baseline: 3.3951x; 1.0744x over previous
//
#include <hip/hip_runtime.h>

#define T_DIM 4096
#define QPR 32            // float4 quads per (b,t) row (D=128)
#define CH 8              // chunk length along t
#define CPS (T_DIM / CH)  // 512 chunks per series

typedef float floatx4 __attribute__((ext_vector_type(4)));  // native vec for NT store

// One thread owns CH=8 consecutive t's of one (b, 4-d) column.
// Forward register scan -> (a, kb); backward register scan -> (b, kf);
// select-free epilogue: fill = a + trel*(b-a)*rcp(max3(trel+kf-1, trel, 1)).
// Round-10 levers:
//  (1) explicit 16-load burst + sched_barrier(0): forces all loads in flight
//      in ONE latency round-trip (compiler was serializing at VGPR=44).
//  (2) XCD swizzle: contiguous t-range per XCD so halo rows (chunk rows of
//      t-adjacent blocks) are same-XCD L2 hits, not L3 hits.
__global__ void __launch_bounds__(256, 4) imputer_kernel(
    const float* __restrict__ x, float* __restrict__ out) {
    // XCD-aware swizzle: gridDim.x = 4096 = 8 * 512 exactly.
    int bid = blockIdx.x;
    int wg  = (bid & 7) * 512 + (bid >> 3);
    int n   = wg * 256 + threadIdx.x;

    int q  = n & (QPR - 1);
    int ch = n >> 5;                  // global chunk id
    int t0 = (ch & (CPS - 1)) << 3;
    int bb = ch >> 9;
    int sb = bb * (T_DIM * QPR) + q;  // quad index of (bb, t=0, q)
    int base = sb + t0 * QPR;

    const float4* __restrict__ x4 = reinterpret_cast<const float4*>(x);

    // ---- LOAD BURST: 8 chunk rows + 4+4 clamped halo rows, then fence ----
    float4 R[CH];
    float4 PM[4], PS[4];
#pragma unroll
    for (int k = 0; k < CH; ++k) R[k] = x4[base + k * QPR];
#pragma unroll
    for (int j = 0; j < 4; ++j) {
        PM[j] = x4[sb + max(t0 - 1 - j, 0) * QPR];
        PS[j] = x4[sb + min(t0 + CH + j, T_DIM - 1) * QPR];
    }
    __builtin_amdgcn_sched_barrier(0);   // keep all 16 loads issued before any use

    float Rv[CH][4];
#pragma unroll
    for (int k = 0; k < CH; ++k) {
        Rv[k][0] = R[k].x; Rv[k][1] = R[k].y; Rv[k][2] = R[k].z; Rv[k][3] = R[k].w;
    }
    float PMv[4][4], PSv[4][4];
#pragma unroll
    for (int j = 0; j < 4; ++j) {
        PMv[j][0] = PM[j].x; PMv[j][1] = PM[j].y; PMv[j][2] = PM[j].z; PMv[j][3] = PM[j].w;
        PSv[j][0] = PS[j].x; PSv[j][1] = PS[j].y; PSv[j][2] = PS[j].z; PSv[j][3] = PS[j].w;
    }

    // ---- prefix merge: state (A, KB) at position t0-1 ----
    float kbmax = (float)max(t0 - 1, 0);
    float A[4], KB[4];
#pragma unroll
    for (int c = 0; c < 4; ++c) { A[c] = 0.f; KB[c] = (float)t0; }  // s=-1 default
#pragma unroll
    for (int j = 0; j < 4; ++j) {
        float kbj = fminf((float)j, kbmax);
#pragma unroll
        for (int c = 0; c < 4; ++c)
            if (A[c] == 0.f && PMv[j][c] != 0.f) { A[c] = PMv[j][c]; KB[c] = kbj; }
    }

    // ---- suffix merge: state (Bt, KF) at position t_end = t0+CH-1 ----
    float kfmax = (float)(T_DIM - CH - t0);   // = (T-1) - t_end
    float Bt[4], KF[4];
#pragma unroll
    for (int c = 0; c < 4; ++c) { Bt[c] = 0.f; KF[c] = kfmax; }  // nv=T default
#pragma unroll
    for (int j = 0; j < 4; ++j) {
        float kfj = fminf((float)(j + 1), kfmax);
#pragma unroll
        for (int c = 0; c < 4; ++c)
            if (Bt[c] == 0.f && PSv[j][c] != 0.f) { Bt[c] = PSv[j][c]; KF[c] = kfj; }
    }

    // ---- deep halo (rare): gap extends past the 4 shallow rows ----
    bool nb = false, nf = false;
#pragma unroll
    for (int c = 0; c < 4; ++c) {
        nb = nb || (A[c] == 0.f && Rv[0][c] == 0.f);
        nf = nf || (Bt[c] == 0.f && Rv[CH - 1][c] == 0.f);
    }
    if (__any(nb && t0 > 4)) {
        if (nb && t0 > 4) {
#pragma unroll
            for (int c = 0; c < 4; ++c) {
                if (A[c] == 0.f && Rv[0][c] == 0.f) {
                    int s = t0 - 5;
                    while (s >= 0 && x[(sb + s * QPR) * 4 + c] == 0.f) --s;
                    if (s >= 0) { A[c] = x[(sb + s * QPR) * 4 + c]; KB[c] = (float)(t0 - 1 - s); }
                    // else: default (A=0, KB=t0) is the correct s=-1 state
                }
            }
        }
    }
    if (__any(nf && (t0 + 12) < T_DIM)) {
        if (nf && (t0 + 12) < T_DIM) {
#pragma unroll
            for (int c = 0; c < 4; ++c) {
                if (Bt[c] == 0.f && Rv[CH - 1][c] == 0.f) {
                    int e = t0 + CH + 4;
                    while (e < T_DIM && x[(sb + e * QPR) * 4 + c] == 0.f) ++e;
                    if (e < T_DIM) { Bt[c] = x[(sb + e * QPR) * 4 + c]; KF[c] = (float)(e - (t0 + CH - 1)); }
                    else           { KF[c] = kfmax; }  // whole tail invalid: b=0, end=T-1
                }
            }
        }
    }

    // ---- forward sweep: per-position (a, kb) ----
    float av[CH][4], kb[CH][4];
#pragma unroll
    for (int k = 0; k < CH; ++k) {
#pragma unroll
        for (int c = 0; c < 4; ++c) {
            bool valid = (Rv[k][c] != 0.f);
            A[c]  = valid ? Rv[k][c] : A[c];
            KB[c] = valid ? 0.f : (KB[c] + 1.f);
            av[k][c] = A[c];
            kb[k][c] = KB[c];
        }
    }

    // ---- backward sweep + select-free epilogue + NT store ----
    float tf = (float)t0;
    floatx4* __restrict__ out4 = reinterpret_cast<floatx4*>(out);
#pragma unroll
    for (int k = CH - 1; k >= 0; --k) {
        float o[4];
#pragma unroll
        for (int c = 0; c < 4; ++c) {
            float trel = fminf(kb[k][c], tf + (float)k);          // min(kb, t)
            float u    = trel + KF[c] - 1.f;                      // denom
            float den  = fmaxf(fmaxf(u, trel), 1.f);              // v_max3
            o[c] = av[k][c] + trel * (Bt[c] - av[k][c]) * __builtin_amdgcn_rcpf(den);
            bool valid = (kb[k][c] == 0.f);
            Bt[c] = valid ? av[k][c] : Bt[c];
            KF[c] = valid ? 1.f : (KF[c] + 1.f);
        }
        floatx4 ov = {o[0], o[1], o[2], o[3]};
        __builtin_nontemporal_store(ov, &out4[base + k * QPR]);
    }
}

extern "C" void kernel_launch(void* const* d_in, const int* in_sizes, int n_in,
                              void* d_out, int out_size, void* d_ws, size_t ws_size,
                              hipStream_t stream) {
    const float* x = (const float*)d_in[0];
    float* out = (float*)d_out;
    int threads = 256;
    int blocks = (in_sizes[0] / 4 / CH) / threads;   // 4096, exact (8 | 4096)
    imputer_kernel<<<blocks, threads, 0, stream>>>(x, out);
}